// Round 10
// baseline (1495.305 us; speedup 1.0000x reference)
//
#include <hip/hip_runtime.h>
#include <hip/hip_bf16.h>

// Problem constants (PentachoronCrossAttention)
#define Bsz   8192
#define Vn    5
#define Dm    1792
#define Hn    14
#define HDm   128
#define Mrows (Bsz * Vn)   // 40960
#define N1    (3 * Dm)     // 5376
#define Kd    Dm           // 1792

typedef float f32x4 __attribute__((ext_vector_type(4)));
typedef short bf16x8 __attribute__((ext_vector_type(8)));

__device__ __forceinline__ ushort f2bf(float f) {
    unsigned u = __float_as_uint(f);
    u += 0x7fffu + ((u >> 16) & 1u);   // round-to-nearest-even
    return (ushort)(u >> 16);
}
__device__ __forceinline__ float bf2f(ushort h) {
    return __uint_as_float(((unsigned)h) << 16);
}

#define AS1(p) ((const __attribute__((address_space(1))) void*)(p))
#define AS3(p) ((__attribute__((address_space(3))) void*)(p))

// ---------------- f32 -> bf16 convert ----------------
__global__ void cvt_kernel(const float* __restrict__ in, ushort* __restrict__ out, int n4) {
    int i = blockIdx.x * blockDim.x + threadIdx.x;
    int stride = gridDim.x * blockDim.x;
    for (int idx = i; idx < n4; idx += stride) {
        float4 v = reinterpret_cast<const float4*>(in)[idx];
        ushort4 o;
        o.x = f2bf(v.x); o.y = f2bf(v.y); o.z = f2bf(v.z); o.w = f2bf(v.w);
        reinterpret_cast<ushort4*>(out)[idx] = o;
    }
}

// ---------------- 256x256 8-phase bf16 GEMM, C = A * Bw^T + bias ----------------
// Round-10: B-fragments load DIRECT from global (L2-resident; grouped raster keeps
// the active K-slices hot). LDS holds A only: 64 KiB = 4 units of 16 KiB
// (buf0.k0@0, buf0.k1@16384, buf1.k0@32768, buf1.k1@49152), unit=[256rows][4x16B],
// swizzle phys_slot = log_slot ^ ((row>>1)&3) (round-5: bank conflicts == 0).
// DS traffic/phase: 32 KB A-reads + 8 KB stage-writes (~400cy) << MFMA 620cy.
// Phase = {MFMAQ(prev frags); [even: VMC(N); ] RDA(next); [odd: STAGE A;
//          sched_barrier; LDB B-frags]; BAR}.
// vmcnt ledger (order per odd phase: STAGE(2) then LDB(4); even phases: none):
//   steady/iter0: ph2 VMC(12) [exact iter0, -4 safe-overwait steady],
//   ph4/6/8 VMC(16) [exact]; peel: 12/10/8; prologue VMC(8).
// sched_barrier(0) pins LDB below STAGE (hoist would corrupt the count; sinking
// only over-waits). Even-phase VMC "memory" clobbers fence cross-phase hoists.
template<bool OUT_BF16>
__global__ __launch_bounds__(512, 2) void gemm8p(
    const ushort* __restrict__ A,
    const ushort* __restrict__ Bw,
    const float* __restrict__ bias,
    void* __restrict__ Cout,
    int M, int N, int K)
{
    __shared__ __align__(16) char smem[65536];

    const int nTN = N >> 8;
    int bid = blockIdx.x;
    int cpx = gridDim.x >> 3;                 // grid % 8 == 0 for both launches
    int swz = (bid & 7) * cpx + (bid >> 3);   // XCD-bijective chunk swizzle
    // grouped raster: G=4 bm-rows per group, bm fastest
    int gsz = 4 * nTN;
    int g = swz / gsz, r = swz - g * gsz;
    int bm = g * 4 + (r & 3);
    int bn = r >> 2;

    int t = threadIdx.x;
    int lane = t & 63, w = t >> 6;
    int wrow = (w >> 2) * 128;                // 2 waves in M
    int wcol = (w & 3) * 64;                  // 4 waves in N
    int fr = lane & 15, fq = lane >> 4;
    int slotC = ((fq ^ ((fr >> 1) & 3)) << 4);   // swizzled 16B slot (lane-const)
    int aOff = (wrow + fr) * 64 + slotC;

    // A staging source (pre-swizzled per-lane global address; LDS dest linear)
    size_t K2 = (size_t)K * 2;
    size_t rowSkip = (size_t)128 * K2;
    int rowL = t >> 2;                                  // 0..127
    int slotSw = (((t & 3) ^ ((t >> 3) & 3)) << 4);     // involution of read swizzle
    const char* aSrc = (const char*)A + (size_t)(bm * 256 + rowL) * K2 + slotSw;

    // B fragment base: lane reads Bw[bn*256 + wcol + ni*16 + fr][fq*8 ..+8)
    const ushort* bB = Bw + (size_t)(bn * 256 + wcol + fr) * K + fq * 8;

    f32x4 acc[8][4] = {};
    bf16x8 af0[4], af1[4], bfA[4], bfB[4];

#define STAGE(UOFF, KT, KH) { \
    const char* _s = aSrc + (size_t)(KT) * 128 + (KH) * 64; \
    __builtin_amdgcn_global_load_lds(AS1(_s), AS3(&smem[(UOFF) + t * 16]), 16, 0, 0); \
    __builtin_amdgcn_global_load_lds(AS1(_s + rowSkip), AS3(&smem[(UOFF) + 8192 + t * 16]), 16, 0, 0); }

#define RDA(DST, UOFF, M0) { \
    DST[0] = *(const bf16x8*)&smem[(UOFF) + ((M0)+0)*1024 + aOff]; \
    DST[1] = *(const bf16x8*)&smem[(UOFF) + ((M0)+1)*1024 + aOff]; \
    DST[2] = *(const bf16x8*)&smem[(UOFF) + ((M0)+2)*1024 + aOff]; \
    DST[3] = *(const bf16x8*)&smem[(UOFF) + ((M0)+3)*1024 + aOff]; }

#define LDB(DST, KT, KS) { \
    const ushort* _b = bB + (size_t)(KT) * 64 + (KS) * 32; \
    DST[0] = *(const bf16x8*)(_b); \
    DST[1] = *(const bf16x8*)(_b + (size_t)16 * K); \
    DST[2] = *(const bf16x8*)(_b + (size_t)32 * K); \
    DST[3] = *(const bf16x8*)(_b + (size_t)48 * K); }

#define MFMAQ(AF, BF, M0) { \
    __builtin_amdgcn_s_setprio(1); \
    _Pragma("unroll") \
    for (int mi = 0; mi < 4; ++mi) { \
      _Pragma("unroll") \
      for (int ni = 0; ni < 4; ++ni) \
        acc[(M0)+mi][ni] = __builtin_amdgcn_mfma_f32_16x16x32_bf16(AF[mi], BF[ni], acc[(M0)+mi][ni], 0, 0, 0); \
    } \
    __builtin_amdgcn_s_setprio(0); }

#define BAR __builtin_amdgcn_s_barrier()
#define SBR __builtin_amdgcn_sched_barrier(0)
#define VMC(N) asm volatile("s_waitcnt vmcnt(" #N ")" ::: "memory")

    // ---- prologue: stage A T0.k0/k1, T1.k0 (6 gloads); load B T0.ks0 ----
    STAGE(0,     0, 0);   // buf0.k0 <- T0.k0
    STAGE(16384, 0, 1);   // buf0.k1 <- T0.k1
    STAGE(32768, 1, 0);   // buf1.k0 <- T1.k0
    SBR;
    LDB(bfA, 0, 0);       // T0.ks0
    VMC(8);               // newer-than-T0.k0 = 4 stage + 4 LDB = 8 -> T0.k0 landed
    BAR;
    RDA(af0, 0, 0);       // T0.k0 m0-3

    const int NIT = K / 128;     // 14 iterations, 2 K-tiles each
    #pragma unroll 1
    for (int it = 0; it < NIT - 1; ++it) {
        int T0 = 2 * it, kt1 = T0 + 1, kt2 = T0 + 2, kt3 = T0 + 3;
        // ph1: MFMA T.ks0 m0-3 | rd af1<-buf0.k0 m4-7 | stage (T+1).k1 | ldb T.ks1
        MFMAQ(af0, bfA, 0); RDA(af1, 0, 4);
        STAGE(49152, kt1, 1); SBR; LDB(bfB, T0, 1);
        BAR;
        // ph2: MFMA T.ks0 m4-7 | VMC(12) | rd af0<-buf0.k1 m0-3
        MFMAQ(af1, bfA, 4); VMC(12); RDA(af0, 16384, 0);
        BAR;
        // ph3: MFMA T.ks1 m0-3 | rd af1<-buf0.k1 m4-7 | stage (T+2).k0 | ldb (T+1).ks0
        MFMAQ(af0, bfB, 0); RDA(af1, 16384, 4);
        STAGE(0, kt2, 0); SBR; LDB(bfA, kt1, 0);
        BAR;
        // ph4: MFMA T.ks1 m4-7 | VMC(16) | rd af0<-buf1.k0 m0-3
        MFMAQ(af1, bfB, 4); VMC(16); RDA(af0, 32768, 0);
        BAR;
        // ph5: MFMA (T+1).ks0 m0-3 | rd af1<-buf1.k0 m4-7 | stage (T+2).k1 | ldb (T+1).ks1
        MFMAQ(af0, bfA, 0); RDA(af1, 32768, 4);
        STAGE(16384, kt2, 1); SBR; LDB(bfB, kt1, 1);
        BAR;
        // ph6: MFMA (T+1).ks0 m4-7 | VMC(16) | rd af0<-buf1.k1 m0-3
        MFMAQ(af1, bfA, 4); VMC(16); RDA(af0, 49152, 0);
        BAR;
        // ph7: MFMA (T+1).ks1 m0-3 | rd af1<-buf1.k1 m4-7 | stage (T+3).k0 | ldb (T+2).ks0
        MFMAQ(af0, bfB, 0); RDA(af1, 49152, 4);
        STAGE(32768, kt3, 0); SBR; LDB(bfA, kt2, 0);
        BAR;
        // ph8: MFMA (T+1).ks1 m4-7 | VMC(16) | rd af0<-buf0.k0(T+2) m0-3
        MFMAQ(af1, bfB, 4); VMC(16); RDA(af0, 0, 0);
        BAR;
    }
    // ---- peeled final iteration (T=2*NIT-2): stage only ph1; tighter vmcnt ----
    {
        int T0 = 2 * NIT - 2, kt1 = T0 + 1;
        MFMAQ(af0, bfA, 0); RDA(af1, 0, 4);
        STAGE(49152, kt1, 1); SBR; LDB(bfB, T0, 1);
        BAR;
        MFMAQ(af1, bfA, 4); VMC(12); RDA(af0, 16384, 0);
        BAR;
        MFMAQ(af0, bfB, 0); RDA(af1, 16384, 4);
        SBR; LDB(bfA, kt1, 0);
        BAR;
        MFMAQ(af1, bfB, 4); VMC(10); RDA(af0, 32768, 0);
        BAR;
        MFMAQ(af0, bfA, 0); RDA(af1, 32768, 4);
        SBR; LDB(bfB, kt1, 1);
        BAR;
        MFMAQ(af1, bfA, 4); VMC(8); RDA(af0, 49152, 0);
        BAR;
        MFMAQ(af0, bfB, 0); RDA(af1, 49152, 4);
        BAR;
        MFMAQ(af1, bfB, 4);
    }

#undef STAGE
#undef RDA
#undef LDB
#undef MFMAQ
#undef BAR
#undef SBR
#undef VMC

    // ---- epilogue: C/D layout col=lane&15, row=(lane>>4)*4+reg ----
    float*  Cf = (float*)Cout;
    ushort* Cb = (ushort*)Cout;
    #pragma unroll
    for (int mi = 0; mi < 8; ++mi) {
        int row0 = bm * 256 + wrow + mi * 16 + fq * 4;
        #pragma unroll
        for (int ni = 0; ni < 4; ++ni) {
            int col = bn * 256 + wcol + ni * 16 + fr;
            float bv = bias[col];
            #pragma unroll
            for (int rr = 0; rr < 4; ++rr) {
                float val = acc[mi][ni][rr] + bv;
                size_t off = (size_t)(row0 + rr) * N + col;
                if (OUT_BF16) Cb[off] = f2bf(val);
                else          Cf[off] = val;
            }
        }
    }
}

// ---------------- tiny 5x5 masked attention, one wave per (b,h) ----------------
__global__ __launch_bounds__(256) void attn_kernel(
    const ushort* __restrict__ qkv,
    const int* __restrict__ adj,
    ushort* __restrict__ outp)
{
    int gw = blockIdx.x * 4 + (threadIdx.x >> 6);
    int lane = threadIdx.x & 63;
    int b = gw / Hn;
    int h = gw - b * Hn;

    const ushort* base = qkv + (size_t)b * 5 * N1 + h * HDm + 2 * lane;
    float q[5][2], k[5][2], v[5][2];
    #pragma unroll
    for (int i = 0; i < 5; ++i) {
        ushort2 qq = *reinterpret_cast<const ushort2*>(base + (size_t)i * N1);
        ushort2 kk = *reinterpret_cast<const ushort2*>(base + (size_t)i * N1 + Dm);
        ushort2 vv = *reinterpret_cast<const ushort2*>(base + (size_t)i * N1 + 2 * Dm);
        q[i][0] = bf2f(qq.x); q[i][1] = bf2f(qq.y);
        k[i][0] = bf2f(kk.x); k[i][1] = bf2f(kk.y);
        v[i][0] = bf2f(vv.x); v[i][1] = bf2f(vv.y);
    }

    float s[5][5];
    #pragma unroll
    for (int i = 0; i < 5; ++i)
        #pragma unroll
        for (int j = 0; j < 5; ++j) {
            float p = q[i][0] * k[j][0] + q[i][1] * k[j][1];
            #pragma unroll
            for (int off = 32; off > 0; off >>= 1)
                p += __shfl_xor(p, off);
            s[i][j] = p;
        }

    const float scale = 0.08838834764831845f;  // 1/sqrt(128)
    float aw[5][5];
    #pragma unroll
    for (int i = 0; i < 5; ++i) {
        float sv[5];
        float mx = -3.0e38f;
        #pragma unroll
        for (int j = 0; j < 5; ++j) {
            float val = s[i][j] * scale + (adj[i * 5 + j] == 0 ? -1e30f : 0.0f);
            sv[j] = val;
            mx = fmaxf(mx, val);
        }
        float denom = 0.0f;
        #pragma unroll
        for (int j = 0; j < 5; ++j) { sv[j] = __expf(sv[j] - mx); denom += sv[j]; }
        float rd = 1.0f / denom;
        #pragma unroll
        for (int j = 0; j < 5; ++j) aw[i][j] = sv[j] * rd;
    }

    ushort* ob = outp + (size_t)b * 5 * Dm + h * HDm + 2 * lane;
    #pragma unroll
    for (int i = 0; i < 5; ++i) {
        float o0 = 0.0f, o1 = 0.0f;
        #pragma unroll
        for (int j = 0; j < 5; ++j) { o0 += aw[i][j] * v[j][0]; o1 += aw[i][j] * v[j][1]; }
        ushort2 ov; ov.x = f2bf(o0); ov.y = f2bf(o1);
        *reinterpret_cast<ushort2*>(ob + (size_t)i * Dm) = ov;
    }
}

extern "C" void kernel_launch(void* const* d_in, const int* in_sizes, int n_in,
                              void* d_out, int out_size, void* d_ws, size_t ws_size,
                              hipStream_t stream) {
    const float* vertices  = (const float*)d_in[0];
    const int*   adjacency = (const int*)  d_in[1];
    const float* w1        = (const float*)d_in[2];
    const float* b1        = (const float*)d_in[3];
    const float* w2        = (const float*)d_in[4];
    const float* b2        = (const float*)d_in[5];
    float* out = (float*)d_out;

    char* ws = (char*)d_ws;
    const size_t vertBytes = (size_t)Mrows * Kd * 2;
    const size_t qkvBytes  = (size_t)Mrows * N1 * 2;
    const size_t w1Bytes   = (size_t)N1 * Kd * 2;
    const size_t w2Bytes   = (size_t)Dm * Dm * 2;
    const size_t needed    = vertBytes + qkvBytes + w1Bytes + w2Bytes;
    if (ws_size < needed) return;

    ushort* vert_bf = (ushort*)ws;
    ushort* qkv_bf  = (ushort*)(ws + vertBytes);
    ushort* w1_bf   = (ushort*)(ws + vertBytes + qkvBytes);
    ushort* w2_bf   = (ushort*)(ws + vertBytes + qkvBytes + w1Bytes);

    cvt_kernel<<<2048, 256, 0, stream>>>(vertices, vert_bf, Mrows * Kd / 4);
    cvt_kernel<<<512,  256, 0, stream>>>(w1, w1_bf, N1 * Kd / 4);
    cvt_kernel<<<256,  256, 0, stream>>>(w2, w2_bf, Dm * Dm / 4);

    // GEMM1: qkv = vertices @ W1^T + b1   (bf16 out). grid 160*21=3360 (%8==0)
    gemm8p<true><<<(Mrows / 256) * (N1 / 256), 512, 0, stream>>>(
        vert_bf, w1_bf, b1, qkv_bf, Mrows, N1, Kd);

    // attention (bf16 attn_out into vert_bf region)
    attn_kernel<<<Bsz * Hn / 4, 256, 0, stream>>>(qkv_bf, adjacency, vert_bf);

    // GEMM2: out = attn_out @ W2^T + b2   (f32 out). grid 160*7=1120 (%8==0)
    gemm8p<false><<<(Mrows / 256) * (Dm / 256), 512, 0, stream>>>(
        vert_bf, w2_bf, b2, out, Mrows, Dm, Kd);
}

// Round 11
// 1190.810 us; speedup vs baseline: 1.2557x; 1.2557x over previous
//
#include <hip/hip_runtime.h>
#include <hip/hip_bf16.h>

// Problem constants (PentachoronCrossAttention)
#define Bsz   8192
#define Vn    5
#define Dm    1792
#define Hn    14
#define HDm   128
#define Mrows (Bsz * Vn)   // 40960
#define N1    (3 * Dm)     // 5376
#define Kd    Dm           // 1792

typedef float f32x4 __attribute__((ext_vector_type(4)));
typedef short bf16x8 __attribute__((ext_vector_type(8)));

__device__ __forceinline__ ushort f2bf(float f) {
    unsigned u = __float_as_uint(f);
    u += 0x7fffu + ((u >> 16) & 1u);   // round-to-nearest-even
    return (ushort)(u >> 16);
}
__device__ __forceinline__ float bf2f(ushort h) {
    return __uint_as_float(((unsigned)h) << 16);
}

#define AS1(p) ((const __attribute__((address_space(1))) void*)(p))
#define AS3(p) ((__attribute__((address_space(3))) void*)(p))

// ---------------- f32 -> bf16 convert ----------------
__global__ void cvt_kernel(const float* __restrict__ in, ushort* __restrict__ out, int n4) {
    int i = blockIdx.x * blockDim.x + threadIdx.x;
    int stride = gridDim.x * blockDim.x;
    for (int idx = i; idx < n4; idx += stride) {
        float4 v = reinterpret_cast<const float4*>(in)[idx];
        ushort4 o;
        o.x = f2bf(v.x); o.y = f2bf(v.y); o.z = f2bf(v.z); o.w = f2bf(v.w);
        reinterpret_cast<ushort4*>(out)[idx] = o;
    }
}

// ---------------- 256x256 8-phase bf16 GEMM, C = A * Bw^T + bias ----------------
// LDS (128 KiB): buf b at b*65536; A k-half kh at +kh*16384; B at +32768+kh*16384.
// Unit = [256 rows][4 slots of 16B], swizzle phys_slot = log_slot ^ ((row>>1)&3)
//   (round-5 verified: SQ_LDS_BANK_CONFLICT == 0).
// Round-11: 2-PHASE WINDOWS. Stages batched on EVEN phases (2 units = 4 loads);
// barrier + VMC(4) only at ODD phase ends. Windows {ph2,ph3},{ph4,ph5},... let
// SIMD-mate waves drift so MFMA and DS pipes overlap (r9's every-phase barrier
// forced lockstep: MFMA 515cy + DS 600cy serialized into 1086cy phases).
// WAR: stage at even p overwrites unit consumed at p-1 (odd); consumer's lgkm
// precedes the (p-1)-end barrier -> safe (all 8 units checked).
// vmcnt ledger: 4 loads/batch at ph2/4/6/8; at each odd-end exactly 8 are
// outstanding and the batch the next window reads is the older 4 -> VMC(4)
// uniform (iter0 verified with prologue VMC(6); peel: 4/4/0).
template<bool OUT_BF16>
__global__ __launch_bounds__(512, 2) void gemm8p(
    const ushort* __restrict__ A,
    const ushort* __restrict__ Bw,
    const float* __restrict__ bias,
    void* __restrict__ Cout,
    int M, int N, int K)
{
    __shared__ __align__(16) char smem[131072];

    const int nTN = N >> 8;
    int bid = blockIdx.x;
    int cpx = gridDim.x >> 3;                 // grid % 8 == 0 for both launches
    int swz = (bid & 7) * cpx + (bid >> 3);   // XCD-bijective chunk swizzle
    // grouped raster: G=4 bm-rows per group, bm fastest
    int gsz = 4 * nTN;
    int g = swz / gsz, r = swz - g * gsz;
    int bm = g * 4 + (r & 3);
    int bn = r >> 2;

    int t = threadIdx.x;
    int lane = t & 63, w = t >> 6;
    int wrow = (w >> 2) * 128;                // 2 waves in M
    int wcol = (w & 3) * 64;                  // 4 waves in N
    int fr = lane & 15, fq = lane >> 4;
    int slotC = ((fq ^ ((fr >> 1) & 3)) << 4);   // swizzled 16B slot (lane-const)
    int aOff = (wrow + fr) * 64 + slotC;
    int bOff = 32768 + (wcol + fr) * 64 + slotC;

    // staging source (pre-swizzled per-lane global address; LDS dest stays linear)
    size_t K2 = (size_t)K * 2;
    size_t rowSkip = (size_t)128 * K2;
    int rowL = t >> 2;                                  // 0..127
    int slotSw = (((t & 3) ^ ((t >> 3) & 3)) << 4);     // involution of read swizzle
    const char* aSrc = (const char*)A + (size_t)(bm * 256 + rowL) * K2 + slotSw;
    const char* bSrc = (const char*)Bw + (size_t)(bn * 256 + rowL) * K2 + slotSw;

    f32x4 acc[8][4] = {};
    bf16x8 af0[4], af1[4], bf0[4], bf1[4];

#define STAGE(SRC, UOFF, KT, KH) { \
    const char* _s = (SRC) + (size_t)(KT) * 128 + (KH) * 64; \
    __builtin_amdgcn_global_load_lds(AS1(_s), AS3(&smem[(UOFF) + t * 16]), 16, 0, 0); \
    __builtin_amdgcn_global_load_lds(AS1(_s + rowSkip), AS3(&smem[(UOFF) + 8192 + t * 16]), 16, 0, 0); }

#define RDA(DST, BUF, KS, M0) { \
    DST[0] = *(const bf16x8*)&smem[(BUF)*65536 + (KS)*16384 + ((M0)+0)*1024 + aOff]; \
    DST[1] = *(const bf16x8*)&smem[(BUF)*65536 + (KS)*16384 + ((M0)+1)*1024 + aOff]; \
    DST[2] = *(const bf16x8*)&smem[(BUF)*65536 + (KS)*16384 + ((M0)+2)*1024 + aOff]; \
    DST[3] = *(const bf16x8*)&smem[(BUF)*65536 + (KS)*16384 + ((M0)+3)*1024 + aOff]; }

#define RDB(DST, BUF, KS) { \
    DST[0] = *(const bf16x8*)&smem[(BUF)*65536 + (KS)*16384 + 0*1024 + bOff]; \
    DST[1] = *(const bf16x8*)&smem[(BUF)*65536 + (KS)*16384 + 1*1024 + bOff]; \
    DST[2] = *(const bf16x8*)&smem[(BUF)*65536 + (KS)*16384 + 2*1024 + bOff]; \
    DST[3] = *(const bf16x8*)&smem[(BUF)*65536 + (KS)*16384 + 3*1024 + bOff]; }

#define MFMAQ(AF, BF, M0) { \
    __builtin_amdgcn_s_setprio(1); \
    _Pragma("unroll") \
    for (int mi = 0; mi < 4; ++mi) { \
      _Pragma("unroll") \
      for (int ni = 0; ni < 4; ++ni) \
        acc[(M0)+mi][ni] = __builtin_amdgcn_mfma_f32_16x16x32_bf16(AF[mi], BF[ni], acc[(M0)+mi][ni], 0, 0, 0); \
    } \
    __builtin_amdgcn_s_setprio(0); }

#define BAR __builtin_amdgcn_s_barrier()
#define VMC(N) asm volatile("s_waitcnt vmcnt(" #N ")" ::: "memory")

    // ---- prologue: stage T0 (4 units) + T1.k0 (2 units) = 12 loads ----
    STAGE(aSrc, 0,      0, 0);   // b0.A.k0  loads 1-2
    STAGE(aSrc, 16384,  0, 1);   // b0.A.k1  loads 3-4
    STAGE(bSrc, 32768,  0, 0);   // b0.B.k0  loads 5-6
    STAGE(bSrc, 49152,  0, 1);   // b0.B.k1  loads 7-8
    STAGE(aSrc, 65536,  1, 0);   // b1.A.k0  loads 9-10
    STAGE(bSrc, 98304,  1, 0);   // b1.B.k0  loads 11-12
    VMC(6);                      // drains 1-6: b0.A.k0/A.k1/B.k0 landed
    BAR;
    RDA(af0, 0, 0, 0); RDB(bf0, 0, 0);   // T0.k0 m0-3 + B.k0

    const int NIT = K / 128;     // 14 iterations, 2 K-tiles each
    #pragma unroll 1
    for (int it = 0; it < NIT - 1; ++it) {
        int kt1 = 2 * it + 1, kt2 = 2 * it + 2, kt3 = 2 * it + 3;
        // ph1: MFMA T.ks0 m0-3 | rd af1<-b0.A.k0 m4-7           || VMC(4); BAR
        MFMAQ(af0, bf0, 0); RDA(af1, 0, 0, 4);
        VMC(4); BAR;
        // ph2: MFMA T.ks0 m4-7 | rd af0<-b0.A.k1, bf1<-b0.B.k1 | stage b1.k1(T+1)
        MFMAQ(af1, bf0, 4); RDA(af0, 0, 1, 0); RDB(bf1, 0, 1);
        STAGE(aSrc, 81920, kt1, 1); STAGE(bSrc, 114688, kt1, 1);
        // ph3: MFMA T.ks1 m0-3 | rd af1<-b0.A.k1 m4-7           || VMC(4); BAR
        MFMAQ(af0, bf1, 0); RDA(af1, 0, 1, 4);
        VMC(4); BAR;
        // ph4: MFMA T.ks1 m4-7 | rd af0<-b1.A.k0, bf0<-b1.B.k0 | stage b0.k0(T+2)
        MFMAQ(af1, bf1, 4); RDA(af0, 1, 0, 0); RDB(bf0, 1, 0);
        STAGE(aSrc, 0, kt2, 0); STAGE(bSrc, 32768, kt2, 0);
        // ph5: MFMA (T+1).ks0 m0-3 | rd af1<-b1.A.k0 m4-7       || VMC(4); BAR
        MFMAQ(af0, bf0, 0); RDA(af1, 1, 0, 4);
        VMC(4); BAR;
        // ph6: MFMA (T+1).ks0 m4-7 | rd af0<-b1.A.k1, bf1<-b1.B.k1 | stage b0.k1(T+2)
        MFMAQ(af1, bf0, 4); RDA(af0, 1, 1, 0); RDB(bf1, 1, 1);
        STAGE(aSrc, 16384, kt2, 1); STAGE(bSrc, 49152, kt2, 1);
        // ph7: MFMA (T+1).ks1 m0-3 | rd af1<-b1.A.k1 m4-7       || VMC(4); BAR
        MFMAQ(af0, bf1, 0); RDA(af1, 1, 1, 4);
        VMC(4); BAR;
        // ph8: MFMA (T+1).ks1 m4-7 | rd af0<-b0.A.k0(T+2), bf0<-b0.B.k0 | stage b1.k0(T+3)
        MFMAQ(af1, bf1, 4); RDA(af0, 0, 0, 0); RDB(bf0, 0, 0);
        STAGE(aSrc, 65536, kt3, 0); STAGE(bSrc, 98304, kt3, 0);
    }
    // ---- peeled final iteration: stage only ph2 ((T+1).k1); VMC 4/4/0 ----
    {
        int kt1 = 2 * NIT - 1;
        MFMAQ(af0, bf0, 0); RDA(af1, 0, 0, 4);
        VMC(4); BAR;
        MFMAQ(af1, bf0, 4); RDA(af0, 0, 1, 0); RDB(bf1, 0, 1);
        STAGE(aSrc, 81920, kt1, 1); STAGE(bSrc, 114688, kt1, 1);
        MFMAQ(af0, bf1, 0); RDA(af1, 0, 1, 4);
        VMC(4); BAR;
        MFMAQ(af1, bf1, 4); RDA(af0, 1, 0, 0); RDB(bf0, 1, 0);
        MFMAQ(af0, bf0, 0); RDA(af1, 1, 0, 4);
        VMC(0); BAR;
        MFMAQ(af1, bf0, 4); RDA(af0, 1, 1, 0); RDB(bf1, 1, 1);
        MFMAQ(af0, bf1, 0); RDA(af1, 1, 1, 4);
        BAR;
        MFMAQ(af1, bf1, 4);
    }

#undef STAGE
#undef RDA
#undef RDB
#undef MFMAQ
#undef BAR
#undef VMC

    // ---- epilogue: C/D layout col=lane&15, row=(lane>>4)*4+reg ----
    float*  Cf = (float*)Cout;
    ushort* Cb = (ushort*)Cout;
    #pragma unroll
    for (int mi = 0; mi < 8; ++mi) {
        int row0 = bm * 256 + wrow + mi * 16 + fq * 4;
        #pragma unroll
        for (int ni = 0; ni < 4; ++ni) {
            int col = bn * 256 + wcol + ni * 16 + fr;
            float bv = bias[col];
            #pragma unroll
            for (int rr = 0; rr < 4; ++rr) {
                float val = acc[mi][ni][rr] + bv;
                size_t off = (size_t)(row0 + rr) * N + col;
                if (OUT_BF16) Cb[off] = f2bf(val);
                else          Cf[off] = val;
            }
        }
    }
}

// ---------------- tiny 5x5 masked attention, one wave per (b,h) ----------------
__global__ __launch_bounds__(256) void attn_kernel(
    const ushort* __restrict__ qkv,
    const int* __restrict__ adj,
    ushort* __restrict__ outp)
{
    int gw = blockIdx.x * 4 + (threadIdx.x >> 6);
    int lane = threadIdx.x & 63;
    int b = gw / Hn;
    int h = gw - b * Hn;

    const ushort* base = qkv + (size_t)b * 5 * N1 + h * HDm + 2 * lane;
    float q[5][2], k[5][2], v[5][2];
    #pragma unroll
    for (int i = 0; i < 5; ++i) {
        ushort2 qq = *reinterpret_cast<const ushort2*>(base + (size_t)i * N1);
        ushort2 kk = *reinterpret_cast<const ushort2*>(base + (size_t)i * N1 + Dm);
        ushort2 vv = *reinterpret_cast<const ushort2*>(base + (size_t)i * N1 + 2 * Dm);
        q[i][0] = bf2f(qq.x); q[i][1] = bf2f(qq.y);
        k[i][0] = bf2f(kk.x); k[i][1] = bf2f(kk.y);
        v[i][0] = bf2f(vv.x); v[i][1] = bf2f(vv.y);
    }

    float s[5][5];
    #pragma unroll
    for (int i = 0; i < 5; ++i)
        #pragma unroll
        for (int j = 0; j < 5; ++j) {
            float p = q[i][0] * k[j][0] + q[i][1] * k[j][1];
            #pragma unroll
            for (int off = 32; off > 0; off >>= 1)
                p += __shfl_xor(p, off);
            s[i][j] = p;
        }

    const float scale = 0.08838834764831845f;  // 1/sqrt(128)
    float aw[5][5];
    #pragma unroll
    for (int i = 0; i < 5; ++i) {
        float sv[5];
        float mx = -3.0e38f;
        #pragma unroll
        for (int j = 0; j < 5; ++j) {
            float val = s[i][j] * scale + (adj[i * 5 + j] == 0 ? -1e30f : 0.0f);
            sv[j] = val;
            mx = fmaxf(mx, val);
        }
        float denom = 0.0f;
        #pragma unroll
        for (int j = 0; j < 5; ++j) { sv[j] = __expf(sv[j] - mx); denom += sv[j]; }
        float rd = 1.0f / denom;
        #pragma unroll
        for (int j = 0; j < 5; ++j) aw[i][j] = sv[j] * rd;
    }

    ushort* ob = outp + (size_t)b * 5 * Dm + h * HDm + 2 * lane;
    #pragma unroll
    for (int i = 0; i < 5; ++i) {
        float o0 = 0.0f, o1 = 0.0f;
        #pragma unroll
        for (int j = 0; j < 5; ++j) { o0 += aw[i][j] * v[j][0]; o1 += aw[i][j] * v[j][1]; }
        ushort2 ov; ov.x = f2bf(o0); ov.y = f2bf(o1);
        *reinterpret_cast<ushort2*>(ob + (size_t)i * Dm) = ov;
    }
}

extern "C" void kernel_launch(void* const* d_in, const int* in_sizes, int n_in,
                              void* d_out, int out_size, void* d_ws, size_t ws_size,
                              hipStream_t stream) {
    const float* vertices  = (const float*)d_in[0];
    const int*   adjacency = (const int*)  d_in[1];
    const float* w1        = (const float*)d_in[2];
    const float* b1        = (const float*)d_in[3];
    const float* w2        = (const float*)d_in[4];
    const float* b2        = (const float*)d_in[5];
    float* out = (float*)d_out;

    char* ws = (char*)d_ws;
    const size_t vertBytes = (size_t)Mrows * Kd * 2;
    const size_t qkvBytes  = (size_t)Mrows * N1 * 2;
    const size_t w1Bytes   = (size_t)N1 * Kd * 2;
    const size_t w2Bytes   = (size_t)Dm * Dm * 2;
    const size_t needed    = vertBytes + qkvBytes + w1Bytes + w2Bytes;
    if (ws_size < needed) return;

    ushort* vert_bf = (ushort*)ws;
    ushort* qkv_bf  = (ushort*)(ws + vertBytes);
    ushort* w1_bf   = (ushort*)(ws + vertBytes + qkvBytes);
    ushort* w2_bf   = (ushort*)(ws + vertBytes + qkvBytes + w1Bytes);

    cvt_kernel<<<2048, 256, 0, stream>>>(vertices, vert_bf, Mrows * Kd / 4);
    cvt_kernel<<<512,  256, 0, stream>>>(w1, w1_bf, N1 * Kd / 4);
    cvt_kernel<<<256,  256, 0, stream>>>(w2, w2_bf, Dm * Dm / 4);

    // GEMM1: qkv = vertices @ W1^T + b1   (bf16 out). grid 160*21=3360 (%8==0)
    gemm8p<true><<<(Mrows / 256) * (N1 / 256), 512, 0, stream>>>(
        vert_bf, w1_bf, b1, qkv_bf, Mrows, N1, Kd);

    // attention (bf16 attn_out into vert_bf region)
    attn_kernel<<<Bsz * Hn / 4, 256, 0, stream>>>(qkv_bf, adjacency, vert_bf);

    // GEMM2: out = attn_out @ W2^T + b2   (f32 out). grid 160*7=1120 (%8==0)
    gemm8p<false><<<(Mrows / 256) * (Dm / 256), 512, 0, stream>>>(
        vert_bf, w2_bf, b2, out, Mrows, Dm, Kd);
}

// Round 12
// 1112.912 us; speedup vs baseline: 1.3436x; 1.0700x over previous
//
#include <hip/hip_runtime.h>
#include <hip/hip_bf16.h>

// Problem constants (PentachoronCrossAttention)
#define Bsz   8192
#define Vn    5
#define Dm    1792
#define Hn    14
#define HDm   128
#define Mrows (Bsz * Vn)   // 40960
#define N1    (3 * Dm)     // 5376
#define Kd    Dm           // 1792

typedef float f32x4 __attribute__((ext_vector_type(4)));
typedef short bf16x8 __attribute__((ext_vector_type(8)));

__device__ __forceinline__ ushort f2bf(float f) {
    unsigned u = __float_as_uint(f);
    u += 0x7fffu + ((u >> 16) & 1u);   // round-to-nearest-even
    return (ushort)(u >> 16);
}
__device__ __forceinline__ float bf2f(ushort h) {
    return __uint_as_float(((unsigned)h) << 16);
}

#define AS1(p) ((const __attribute__((address_space(1))) void*)(p))
#define AS3(p) ((__attribute__((address_space(3))) void*)(p))

// ---------------- fused f32 -> bf16 convert (3 regions, one launch) ----------------
__global__ void cvt3_kernel(const float* __restrict__ in0, ushort* __restrict__ out0, int n0,
                            const float* __restrict__ in1, ushort* __restrict__ out1, int n1,
                            const float* __restrict__ in2, ushort* __restrict__ out2, int n2) {
    int i = blockIdx.x * blockDim.x + threadIdx.x;
    int stride = gridDim.x * blockDim.x;
    int ntot = n0 + n1 + n2;
    for (int idx = i; idx < ntot; idx += stride) {
        const float* src; ushort* dst; int k;
        if (idx < n0)            { src = in0; dst = out0; k = idx; }
        else if (idx < n0 + n1)  { src = in1; dst = out1; k = idx - n0; }
        else                     { src = in2; dst = out2; k = idx - n0 - n1; }
        float4 v = reinterpret_cast<const float4*>(src)[k];
        ushort4 o;
        o.x = f2bf(v.x); o.y = f2bf(v.y); o.z = f2bf(v.z); o.w = f2bf(v.w);
        reinterpret_cast<ushort4*>(dst)[k] = o;
    }
}

// ---------------- 256x256 8-phase bf16 GEMM, C = A * Bw^T + bias ----------------
// FROZEN at round-11 (best: GEMM1 658us, MfmaUtil 58%, bank-conflicts 0).
// LDS (128 KiB): buf b at b*65536; A k-half kh at +kh*16384; B at +32768+kh*16384.
// Unit = [256 rows][4 slots of 16B], swizzle phys_slot = log_slot ^ ((row>>1)&3).
// 2-phase windows: stages batched on EVEN phases; barrier + VMC(4) at ODD ends.
// WAR: stage at even p overwrites unit consumed at p-1 (odd). vmcnt ledger:
// VMC(4) uniform steady; prologue VMC(6); peel 4/4/0. Grouped raster (G=4).
template<bool OUT_BF16>
__global__ __launch_bounds__(512, 2) void gemm8p(
    const ushort* __restrict__ A,
    const ushort* __restrict__ Bw,
    const float* __restrict__ bias,
    void* __restrict__ Cout,
    int M, int N, int K)
{
    __shared__ __align__(16) char smem[131072];

    const int nTN = N >> 8;
    int bid = blockIdx.x;
    int cpx = gridDim.x >> 3;                 // grid % 8 == 0 for both launches
    int swz = (bid & 7) * cpx + (bid >> 3);   // XCD-bijective chunk swizzle
    int gsz = 4 * nTN;
    int g = swz / gsz, r = swz - g * gsz;
    int bm = g * 4 + (r & 3);
    int bn = r >> 2;

    int t = threadIdx.x;
    int lane = t & 63, w = t >> 6;
    int wrow = (w >> 2) * 128;                // 2 waves in M
    int wcol = (w & 3) * 64;                  // 4 waves in N
    int fr = lane & 15, fq = lane >> 4;
    int slotC = ((fq ^ ((fr >> 1) & 3)) << 4);   // swizzled 16B slot (lane-const)
    int aOff = (wrow + fr) * 64 + slotC;
    int bOff = 32768 + (wcol + fr) * 64 + slotC;

    size_t K2 = (size_t)K * 2;
    size_t rowSkip = (size_t)128 * K2;
    int rowL = t >> 2;                                  // 0..127
    int slotSw = (((t & 3) ^ ((t >> 3) & 3)) << 4);     // involution of read swizzle
    const char* aSrc = (const char*)A + (size_t)(bm * 256 + rowL) * K2 + slotSw;
    const char* bSrc = (const char*)Bw + (size_t)(bn * 256 + rowL) * K2 + slotSw;

    f32x4 acc[8][4] = {};
    bf16x8 af0[4], af1[4], bf0[4], bf1[4];

#define STAGE(SRC, UOFF, KT, KH) { \
    const char* _s = (SRC) + (size_t)(KT) * 128 + (KH) * 64; \
    __builtin_amdgcn_global_load_lds(AS1(_s), AS3(&smem[(UOFF) + t * 16]), 16, 0, 0); \
    __builtin_amdgcn_global_load_lds(AS1(_s + rowSkip), AS3(&smem[(UOFF) + 8192 + t * 16]), 16, 0, 0); }

#define RDA(DST, BUF, KS, M0) { \
    DST[0] = *(const bf16x8*)&smem[(BUF)*65536 + (KS)*16384 + ((M0)+0)*1024 + aOff]; \
    DST[1] = *(const bf16x8*)&smem[(BUF)*65536 + (KS)*16384 + ((M0)+1)*1024 + aOff]; \
    DST[2] = *(const bf16x8*)&smem[(BUF)*65536 + (KS)*16384 + ((M0)+2)*1024 + aOff]; \
    DST[3] = *(const bf16x8*)&smem[(BUF)*65536 + (KS)*16384 + ((M0)+3)*1024 + aOff]; }

#define RDB(DST, BUF, KS) { \
    DST[0] = *(const bf16x8*)&smem[(BUF)*65536 + (KS)*16384 + 0*1024 + bOff]; \
    DST[1] = *(const bf16x8*)&smem[(BUF)*65536 + (KS)*16384 + 1*1024 + bOff]; \
    DST[2] = *(const bf16x8*)&smem[(BUF)*65536 + (KS)*16384 + 2*1024 + bOff]; \
    DST[3] = *(const bf16x8*)&smem[(BUF)*65536 + (KS)*16384 + 3*1024 + bOff]; }

#define MFMAQ(AF, BF, M0) { \
    __builtin_amdgcn_s_setprio(1); \
    _Pragma("unroll") \
    for (int mi = 0; mi < 4; ++mi) { \
      _Pragma("unroll") \
      for (int ni = 0; ni < 4; ++ni) \
        acc[(M0)+mi][ni] = __builtin_amdgcn_mfma_f32_16x16x32_bf16(AF[mi], BF[ni], acc[(M0)+mi][ni], 0, 0, 0); \
    } \
    __builtin_amdgcn_s_setprio(0); }

#define BAR __builtin_amdgcn_s_barrier()
#define VMC(N) asm volatile("s_waitcnt vmcnt(" #N ")" ::: "memory")

    // ---- prologue: stage T0 (4 units) + T1.k0 (2 units) = 12 loads ----
    STAGE(aSrc, 0,      0, 0);
    STAGE(aSrc, 16384,  0, 1);
    STAGE(bSrc, 32768,  0, 0);
    STAGE(bSrc, 49152,  0, 1);
    STAGE(aSrc, 65536,  1, 0);
    STAGE(bSrc, 98304,  1, 0);
    VMC(6);
    BAR;
    RDA(af0, 0, 0, 0); RDB(bf0, 0, 0);

    const int NIT = K / 128;     // 14 iterations, 2 K-tiles each
    #pragma unroll 1
    for (int it = 0; it < NIT - 1; ++it) {
        int kt1 = 2 * it + 1, kt2 = 2 * it + 2, kt3 = 2 * it + 3;
        MFMAQ(af0, bf0, 0); RDA(af1, 0, 0, 4);
        VMC(4); BAR;
        MFMAQ(af1, bf0, 4); RDA(af0, 0, 1, 0); RDB(bf1, 0, 1);
        STAGE(aSrc, 81920, kt1, 1); STAGE(bSrc, 114688, kt1, 1);
        MFMAQ(af0, bf1, 0); RDA(af1, 0, 1, 4);
        VMC(4); BAR;
        MFMAQ(af1, bf1, 4); RDA(af0, 1, 0, 0); RDB(bf0, 1, 0);
        STAGE(aSrc, 0, kt2, 0); STAGE(bSrc, 32768, kt2, 0);
        MFMAQ(af0, bf0, 0); RDA(af1, 1, 0, 4);
        VMC(4); BAR;
        MFMAQ(af1, bf0, 4); RDA(af0, 1, 1, 0); RDB(bf1, 1, 1);
        STAGE(aSrc, 16384, kt2, 1); STAGE(bSrc, 49152, kt2, 1);
        MFMAQ(af0, bf1, 0); RDA(af1, 1, 1, 4);
        VMC(4); BAR;
        MFMAQ(af1, bf1, 4); RDA(af0, 0, 0, 0); RDB(bf0, 0, 0);
        STAGE(aSrc, 65536, kt3, 0); STAGE(bSrc, 98304, kt3, 0);
    }
    // ---- peeled final iteration ----
    {
        int kt1 = 2 * NIT - 1;
        MFMAQ(af0, bf0, 0); RDA(af1, 0, 0, 4);
        VMC(4); BAR;
        MFMAQ(af1, bf0, 4); RDA(af0, 0, 1, 0); RDB(bf1, 0, 1);
        STAGE(aSrc, 81920, kt1, 1); STAGE(bSrc, 114688, kt1, 1);
        MFMAQ(af0, bf1, 0); RDA(af1, 0, 1, 4);
        VMC(4); BAR;
        MFMAQ(af1, bf1, 4); RDA(af0, 1, 0, 0); RDB(bf0, 1, 0);
        MFMAQ(af0, bf0, 0); RDA(af1, 1, 0, 4);
        VMC(0); BAR;
        MFMAQ(af1, bf0, 4); RDA(af0, 1, 1, 0); RDB(bf1, 1, 1);
        MFMAQ(af0, bf1, 0); RDA(af1, 1, 1, 4);
        BAR;
        MFMAQ(af1, bf1, 4);
    }

#undef STAGE
#undef RDA
#undef RDB
#undef MFMAQ
#undef BAR
#undef VMC

    // ---- epilogue: C/D layout col=lane&15, row=(lane>>4)*4+reg ----
    float*  Cf = (float*)Cout;
    ushort* Cb = (ushort*)Cout;
    #pragma unroll
    for (int mi = 0; mi < 8; ++mi) {
        int row0 = bm * 256 + wrow + mi * 16 + fq * 4;
        #pragma unroll
        for (int ni = 0; ni < 4; ++ni) {
            int col = bn * 256 + wcol + ni * 16 + fr;
            float bv = bias[col];
            #pragma unroll
            for (int rr = 0; rr < 4; ++rr) {
                float val = acc[mi][ni][rr] + bv;
                size_t off = (size_t)(row0 + rr) * N + col;
                if (OUT_BF16) Cb[off] = f2bf(val);
                else          Cf[off] = val;
            }
        }
    }
}

// ---------------- 5x5 masked attention, 2 (b,h) pairs per wave ----------------
// Round-12: 8B/lane vectorization. Lanes 0-31 = pair0, lanes 32-63 = pair1.
// Lane (l&31) owns head dims 4*(l&31)..+3 (ushort4). Per 32-lane group:
// loads/stores are 32x8B = 256B contiguous; dot reduce via shfl_xor 16..1
// (offsets <32 never cross the half-wave boundary).
__global__ __launch_bounds__(256) void attn_kernel(
    const ushort* __restrict__ qkv,
    const int* __restrict__ adj,
    ushort* __restrict__ outp)
{
    int gw = blockIdx.x * 8 + (threadIdx.x >> 5);  // (b,h) pair index
    int l2 = threadIdx.x & 31;
    int b = gw / Hn;
    int h = gw - b * Hn;

    const ushort* base = qkv + (size_t)b * 5 * N1 + h * HDm + 4 * l2;
    float q[5][4], k[5][4], v[5][4];
    #pragma unroll
    for (int i = 0; i < 5; ++i) {
        ushort4 qq = *reinterpret_cast<const ushort4*>(base + (size_t)i * N1);
        ushort4 kk = *reinterpret_cast<const ushort4*>(base + (size_t)i * N1 + Dm);
        ushort4 vv = *reinterpret_cast<const ushort4*>(base + (size_t)i * N1 + 2 * Dm);
        q[i][0] = bf2f(qq.x); q[i][1] = bf2f(qq.y); q[i][2] = bf2f(qq.z); q[i][3] = bf2f(qq.w);
        k[i][0] = bf2f(kk.x); k[i][1] = bf2f(kk.y); k[i][2] = bf2f(kk.z); k[i][3] = bf2f(kk.w);
        v[i][0] = bf2f(vv.x); v[i][1] = bf2f(vv.y); v[i][2] = bf2f(vv.z); v[i][3] = bf2f(vv.w);
    }

    float s[5][5];
    #pragma unroll
    for (int i = 0; i < 5; ++i)
        #pragma unroll
        for (int j = 0; j < 5; ++j) {
            float p = q[i][0] * k[j][0] + q[i][1] * k[j][1]
                    + q[i][2] * k[j][2] + q[i][3] * k[j][3];
            #pragma unroll
            for (int off = 16; off > 0; off >>= 1)
                p += __shfl_xor(p, off);
            s[i][j] = p;
        }

    const float scale = 0.08838834764831845f;  // 1/sqrt(128)
    float aw[5][5];
    #pragma unroll
    for (int i = 0; i < 5; ++i) {
        float sv[5];
        float mx = -3.0e38f;
        #pragma unroll
        for (int j = 0; j < 5; ++j) {
            float val = s[i][j] * scale + (adj[i * 5 + j] == 0 ? -1e30f : 0.0f);
            sv[j] = val;
            mx = fmaxf(mx, val);
        }
        float denom = 0.0f;
        #pragma unroll
        for (int j = 0; j < 5; ++j) { sv[j] = __expf(sv[j] - mx); denom += sv[j]; }
        float rd = 1.0f / denom;
        #pragma unroll
        for (int j = 0; j < 5; ++j) aw[i][j] = sv[j] * rd;
    }

    ushort* ob = outp + (size_t)b * 5 * Dm + h * HDm + 4 * l2;
    #pragma unroll
    for (int i = 0; i < 5; ++i) {
        float o0 = 0.0f, o1 = 0.0f, o2 = 0.0f, o3 = 0.0f;
        #pragma unroll
        for (int j = 0; j < 5; ++j) {
            o0 += aw[i][j] * v[j][0]; o1 += aw[i][j] * v[j][1];
            o2 += aw[i][j] * v[j][2]; o3 += aw[i][j] * v[j][3];
        }
        ushort4 ov;
        ov.x = f2bf(o0); ov.y = f2bf(o1); ov.z = f2bf(o2); ov.w = f2bf(o3);
        *reinterpret_cast<ushort4*>(ob + (size_t)i * Dm) = ov;
    }
}

extern "C" void kernel_launch(void* const* d_in, const int* in_sizes, int n_in,
                              void* d_out, int out_size, void* d_ws, size_t ws_size,
                              hipStream_t stream) {
    const float* vertices  = (const float*)d_in[0];
    const int*   adjacency = (const int*)  d_in[1];
    const float* w1        = (const float*)d_in[2];
    const float* b1        = (const float*)d_in[3];
    const float* w2        = (const float*)d_in[4];
    const float* b2        = (const float*)d_in[5];
    float* out = (float*)d_out;

    char* ws = (char*)d_ws;
    const size_t vertBytes = (size_t)Mrows * Kd * 2;
    const size_t qkvBytes  = (size_t)Mrows * N1 * 2;
    const size_t w1Bytes   = (size_t)N1 * Kd * 2;
    const size_t w2Bytes   = (size_t)Dm * Dm * 2;
    const size_t needed    = vertBytes + qkvBytes + w1Bytes + w2Bytes;
    if (ws_size < needed) return;

    ushort* vert_bf = (ushort*)ws;
    ushort* qkv_bf  = (ushort*)(ws + vertBytes);
    ushort* w1_bf   = (ushort*)(ws + vertBytes + qkvBytes);
    ushort* w2_bf   = (ushort*)(ws + vertBytes + qkvBytes + w1Bytes);

    // single fused conversion launch (3 regions)
    cvt3_kernel<<<2048, 256, 0, stream>>>(
        vertices, vert_bf, Mrows * Kd / 4,
        w1, w1_bf, N1 * Kd / 4,
        w2, w2_bf, Dm * Dm / 4);

    // GEMM1: qkv = vertices @ W1^T + b1   (bf16 out). grid 160*21=3360 (%8==0)
    gemm8p<true><<<(Mrows / 256) * (N1 / 256), 512, 0, stream>>>(
        vert_bf, w1_bf, b1, qkv_bf, Mrows, N1, Kd);

    // attention: 2 pairs/wave, 8 pairs/block -> 14336 blocks
    attn_kernel<<<Bsz * Hn / 8, 256, 0, stream>>>(qkv_bf, adjacency, vert_bf);

    // GEMM2: out = attn_out @ W2^T + b2   (f32 out). grid 160*7=1120 (%8==0)
    gemm8p<false><<<(Mrows / 256) * (Dm / 256), 512, 0, stream>>>(
        vert_bf, w2_bf, b2, out, Mrows, Dm, Kd);
}